// Round 3
// baseline (120.982 us; speedup 1.0000x reference)
//
#include <hip/hip_runtime.h>
#include <math.h>

#define SA 20        // alphabet
#define KDIM 2
#define MDIM 2
#define BDIM 512
#define LDIM 512
#define NRATES 512
#define NCH (LDIM * KDIM * SA / 4)    // 5120 float4 chunks per (m,b) pair
#define GBLK_PER_PAIR 4               // gather blocks per pair
#define GCHUNK (NCH / GBLK_PER_PAIR)  // 1280 chunks per gather block
#define GITER (GCHUNK / 256)          // 5 chunks per thread

__device__ __forceinline__ float softplusf(float x) {
    return fmaxf(x, 0.0f) + log1pf(expf(-fabsf(x)));
}

// C(row-per-lane regs) = A(regs) * B (LDS 20x20 row-major, 16B aligned rows via
// contiguous 400-float blocks). Same-address float4 reads broadcast.
__device__ __forceinline__ void mmB(float* C, const float* A, const float* Bl) {
    #pragma unroll
    for (int j = 0; j < SA; ++j) C[j] = 0.0f;
    #pragma unroll
    for (int t = 0; t < SA; ++t) {
        const float a = A[t];
        const float4* row = reinterpret_cast<const float4*>(Bl + t * SA);
        #pragma unroll
        for (int q = 0; q < 5; ++q) {
            float4 b = row[q];
            C[4*q+0] = fmaf(a, b.x, C[4*q+0]);
            C[4*q+1] = fmaf(a, b.y, C[4*q+1]);
            C[4*q+2] = fmaf(a, b.z, C[4*q+2]);
            C[4*q+3] = fmaf(a, b.w, C[4*q+3]);
        }
    }
}

__device__ __forceinline__ void stageRow(float* dst, const float* T, int row, bool act) {
    if (act) {
        float4* d4 = reinterpret_cast<float4*>(dst + row * SA);
        #pragma unroll
        for (int q = 0; q < 5; ++q)
            d4[q] = make_float4(T[4*q+0], T[4*q+1], T[4*q+2], T[4*q+3]);
    }
}

// ---------------- Kernel A: fused qmat + expm, one (m,b) pair per block -----
__global__ __launch_bounds__(64) void expm_kernel(
    const int*   __restrict__ rateIdx,
    const float* __restrict__ tauk,
    const float* __restrict__ Ek,
    const float* __restrict__ eqk,
    float*       __restrict__ Pg)      // (1024, 2, 20, 20)
{
    __shared__ float sStage[KDIM * SA * SA];   // 800 floats

    const int lane = threadIdx.x;       // one wave
    const int mb   = blockIdx.x;        // pair in [0, 1024)
    const int mm   = mb >> 9;           // BDIM = 512

    const int  half = lane >> 5;        // which k
    const int  row  = lane & 31;
    const bool act  = row < SA;
    const int  mk   = mm * KDIM + half;
    float* stage = sStage + half * SA * SA;

    // p = softmax(eqk)
    float e = act ? eqk[mk * SA + row] : -INFINITY;
    float mx = e;
    #pragma unroll
    for (int off = 16; off; off >>= 1) mx = fmaxf(mx, __shfl_xor(mx, off, 32));
    float ex = act ? expf(e - mx) : 0.0f;
    float sm = ex;
    #pragma unroll
    for (int off = 16; off; off >>= 1) sm += __shfl_xor(sm, off, 32);
    float p_i = ex / sm;

    // R = softplus(sym(Ek)) off-diag; Q = R*p - diag(rowsum); normalize by mue
    const int r0 = act ? row : 0;
    float A[SA];
    float dg = 0.0f;
    #pragma unroll
    for (int j = 0; j < SA; ++j) {
        float pj = __shfl(p_i, j, 32);
        float e1 = Ek[(mk * SA + r0) * SA + j];
        float e2 = Ek[(mk * SA + j) * SA + r0];
        float r  = (j == row) ? 0.0f : softplusf(0.5f * (e1 + e2));
        float q  = r * pj;
        A[j] = q;
        dg  += q;
    }
    float t_ = act ? p_i * dg : 0.0f;
    #pragma unroll
    for (int off = 16; off; off >>= 1) t_ += __shfl_xor(t_, off, 32);
    const float inv = 1.0f / fmaxf(t_, 1e-16f);

    const float tau = softplusf(tauk[mm * NRATES + rateIdx[mb]]);
    const float sc  = tau * inv;
    #pragma unroll
    for (int j = 0; j < SA; ++j)
        A[j] = act ? ((j == row) ? -dg * sc : A[j] * sc) : 0.0f;

    // scaling: s = ceil(log2(||A||inf)), theta = 1.0
    float rn = 0.0f;
    #pragma unroll
    for (int j = 0; j < SA; ++j) rn += fabsf(A[j]);
    #pragma unroll
    for (int off = 16; off; off >>= 1) rn = fmaxf(rn, __shfl_xor(rn, off, 32));
    int s = 0;
    if (rn > 1.0f) s = (int)ceilf(log2f(rn));
    if (s < 0) s = 0;
    if (s > 30) s = 30;
    const float scale = exp2f((float)(-s));
    #pragma unroll
    for (int j = 0; j < SA; ++j) A[j] *= scale;
    const int smax = max(s, __shfl_xor(s, 32, 64));

    // degree-6 Paterson-Stockmeyer Taylor: 3 matmuls
    float A2[SA], A3[SA], T[SA];
    stageRow(stage, A, row, act);
    mmB(A2, A, stage);
    mmB(A3, A2, stage);
    #pragma unroll
    for (int j = 0; j < SA; ++j) {
        float id = (j == row) ? 1.0f : 0.0f;
        T[j] = (1.0f/6.0f)*id + (1.0f/24.0f)*A[j] + (1.0f/120.0f)*A2[j] + (1.0f/720.0f)*A3[j];
    }
    stageRow(stage, T, row, act);      // stage B1
    {
        float P1[SA];
        mmB(P1, A3, stage);
        #pragma unroll
        for (int j = 0; j < SA; ++j) {
            float id = (j == row) ? 1.0f : 0.0f;
            T[j] = P1[j] + id + A[j] + 0.5f * A2[j];
        }
    }
    for (int it = 0; it < smax; ++it) {
        stageRow(stage, T, row, act);
        float Tn[SA];
        mmB(Tn, T, stage);
        const bool doit = it < s;
        #pragma unroll
        for (int j = 0; j < SA; ++j) T[j] = doit ? Tn[j] : T[j];
    }

    // write P rows: Pg[mb, half, row, :]
    if (act) {
        float4* d4 = reinterpret_cast<float4*>(Pg + ((size_t)mb * KDIM + half) * SA * SA + row * SA);
        #pragma unroll
        for (int q = 0; q < 5; ++q)
            d4[q] = make_float4(T[4*q+0], T[4*q+1], T[4*q+2], T[4*q+3]);
    }
}

// ---------------- Kernel B: gather + stream out, no LDS, no barriers -------
__global__ __launch_bounds__(256) void gather_kernel(
    const int*   __restrict__ seqg,
    const float* __restrict__ Pg,
    float*       __restrict__ out)
{
    const int tid   = threadIdx.x;
    const int mb    = blockIdx.x >> 2;                      // pair
    const int cbase = (blockIdx.x & 3) * GCHUNK + tid;      // chunk within pair

    const int*    sq = seqg + (size_t)mb * LDIM;
    const float4* P4 = reinterpret_cast<const float4*>(Pg + (size_t)mb * KDIM * SA * SA);
    float4*       o4 = reinterpret_cast<float4*>(out) + (size_t)mb * NCH;

    int c[GITER], l[GITER], sqv[GITER], idx[GITER];
    #pragma unroll
    for (int i = 0; i < GITER; ++i) c[i] = cbase + i * 256;
    #pragma unroll
    for (int i = 0; i < GITER; ++i) l[i] = c[i] / 10;
    #pragma unroll
    for (int i = 0; i < GITER; ++i) sqv[i] = sq[l[i]];
    #pragma unroll
    for (int i = 0; i < GITER; ++i) {
        int ch = c[i] - l[i] * 10;
        int kk = (ch >= 5) ? 1 : 0;
        int c4 = ch - kk * 5;
        idx[i] = (kk * SA + sqv[i]) * 5 + c4;
    }
    float4 v[GITER];
    #pragma unroll
    for (int i = 0; i < GITER; ++i) v[i] = P4[idx[i]];
    #pragma unroll
    for (int i = 0; i < GITER; ++i) o4[c[i]] = v[i];
}

extern "C" void kernel_launch(void* const* d_in, const int* in_sizes, int n_in,
                              void* d_out, int out_size, void* d_ws, size_t ws_size,
                              hipStream_t stream) {
    const int*   seq  = (const int*)d_in[0];
    const int*   ridx = (const int*)d_in[1];
    const float* tauk = (const float*)d_in[2];
    const float* Ek   = (const float*)d_in[3];
    const float* eqk  = (const float*)d_in[4];
    float* out = (float*)d_out;
    float* Pg  = (float*)d_ws;   // 1024*2*20*20 floats = 3.2 MB

    expm_kernel<<<MDIM * BDIM, 64, 0, stream>>>(ridx, tauk, Ek, eqk, Pg);
    gather_kernel<<<MDIM * BDIM * GBLK_PER_PAIR, 256, 0, stream>>>(seq, Pg, out);
}